// Round 19
// baseline (555.490 us; speedup 1.0000x reference)
//
#include <hip/hip_runtime.h>
#include <hip/hip_bf16.h>
#include <cstddef>
#include <cstdint>

typedef __hip_bfloat16 bf16;
typedef __attribute__((ext_vector_type(2))) _Float16 half2v;
typedef __attribute__((ext_vector_type(8))) _Float16 half8;
typedef __attribute__((ext_vector_type(8))) short short8;
typedef __attribute__((ext_vector_type(4))) float f32x4;
typedef __attribute__((ext_vector_type(2))) unsigned long long u64x2;

// ---------- helpers ----------
__device__ inline float ldf(const float* p) { return *p; }
__device__ inline float ldf(const bf16* p) { return __bfloat162float(*p); }
__device__ inline void stf(float* p, float v) { *p = v; }
__device__ inline void stf(bf16* p, float v) { *p = __float2bfloat16(v); }
__device__ inline short bfb(float v) { return __builtin_bit_cast(short, __float2bfloat16(v)); }

__device__ inline half8 h8_from(unsigned long long lo, unsigned long long hi) {
    u64x2 t; t.x = lo; t.y = hi;
    return __builtin_bit_cast(half8, t);
}
__device__ inline float fsig(float x) {
    x = fminf(fmaxf(x, -60.f), 60.f);
    return 1.f / (1.f + __expf(-x));
}
__device__ inline float ftanh(float x) {
    x = fminf(fmaxf(x, -15.f), 15.f);
    float e = __expf(2.f * x);
    return 1.f - 2.f / (e + 1.f);
}
__device__ inline void unpack8(uint4 u, float4& lo, float4& hi) {
    uint32_t w0 = u.x, w1 = u.y, w2 = u.z, w3 = u.w;
    lo.x = __builtin_bit_cast(float, (w0 & 0xffffu) << 16);
    lo.y = __builtin_bit_cast(float, w0 & 0xffff0000u);
    lo.z = __builtin_bit_cast(float, (w1 & 0xffffu) << 16);
    lo.w = __builtin_bit_cast(float, w1 & 0xffff0000u);
    hi.x = __builtin_bit_cast(float, (w2 & 0xffffu) << 16);
    hi.y = __builtin_bit_cast(float, w2 & 0xffff0000u);
    hi.z = __builtin_bit_cast(float, (w3 & 0xffffu) << 16);
    hi.w = __builtin_bit_cast(float, w3 & 0xffff0000u);
}
__device__ inline uint32_t pk2(float a, float b) {
    return ((uint32_t)(uint16_t)bfb(a)) | (((uint32_t)(uint16_t)bfb(b)) << 16);
}

// Problem constants: BS=32, T=64, NE=32, NA=8, ED=128, H=512, A=512, NH=8, HD=64, NACT=32

// ---------- MFMA bf16 GEMM, 2-phase double-buffered staging ----------
template<int ACT, bool QG, typename TA, typename TC>
__global__ __launch_bounds__(256) void mfma_gemm_k(
    const TA* __restrict__ A, const bf16* __restrict__ Bt,
    const float* __restrict__ bias, TC* __restrict__ C,
    int M, int N, int K)
{
    __shared__ short As[2][4096];
    __shared__ short Bs[2][4096];
    const int tid = threadIdx.x;
    const int lane = tid & 63, wid = tid >> 6;
    const int wm = wid >> 1, wn = wid & 1;
    const int bm = blockIdx.y * 128, bn = blockIdx.x * 128;
    const int fr = lane & 15, fq = lane >> 4;

    f32x4 acc[4][4] = {};

    auto stage = [&](int buf, int k0) {
#if __has_builtin(__builtin_amdgcn_global_load_lds)
        #pragma unroll
        for (int j = 0; j < 2; ++j) {
            int jj = wid * 2 + j;
            int row = jj * 16 + (lane >> 2);
            const short* src = (const short*)Bt + (size_t)(bn + row) * K + k0 + (lane & 3) * 8;
            __builtin_amdgcn_global_load_lds(
                (const __attribute__((address_space(1))) void*)src,
                (__attribute__((address_space(3))) void*)&Bs[buf][jj * 512], 16, 0, 0);
        }
        if constexpr (sizeof(TA) == 2) {
            #pragma unroll
            for (int j = 0; j < 2; ++j) {
                int jj = wid * 2 + j;
                int row = jj * 16 + (lane >> 2);
                int gm = bm + row;
                int ar = QG ? (((gm >> 3) << 5) | (gm & 7)) : gm;
                const short* src = (const short*)A + (size_t)ar * K + k0 + (lane & 3) * 8;
                __builtin_amdgcn_global_load_lds(
                    (const __attribute__((address_space(1))) void*)src,
                    (__attribute__((address_space(3))) void*)&As[buf][jj * 512], 16, 0, 0);
            }
        } else {
            int sr = tid >> 1, sk = (tid & 1) * 16;
            int gm = bm + sr;
            int ar = QG ? (((gm >> 3) << 5) | (gm & 7)) : gm;
            const float* ap = (const float*)A + (size_t)ar * K + k0 + sk;
            float4 f0 = *(const float4*)(ap);
            float4 f1 = *(const float4*)(ap + 4);
            float4 f2 = *(const float4*)(ap + 8);
            float4 f3 = *(const float4*)(ap + 12);
            short tmp[16] = {bfb(f0.x), bfb(f0.y), bfb(f0.z), bfb(f0.w),
                             bfb(f1.x), bfb(f1.y), bfb(f1.z), bfb(f1.w),
                             bfb(f2.x), bfb(f2.y), bfb(f2.z), bfb(f2.w),
                             bfb(f3.x), bfb(f3.y), bfb(f3.z), bfb(f3.w)};
            *(uint4*)&As[buf][sr * 32 + sk]     = *(const uint4*)&tmp[0];
            *(uint4*)&As[buf][sr * 32 + sk + 8] = *(const uint4*)&tmp[8];
        }
#else
        {
            int sr = tid >> 1, sk = (tid & 1) * 16;
            int gm = bm + sr;
            int ar = QG ? (((gm >> 3) << 5) | (gm & 7)) : gm;
            if constexpr (sizeof(TA) == 4) {
                const float* ap = (const float*)A + (size_t)ar * K + k0 + sk;
                short tmp[16];
                #pragma unroll
                for (int j = 0; j < 16; ++j) tmp[j] = bfb(ap[j]);
                *(uint4*)&As[buf][sr * 32 + sk]     = *(const uint4*)&tmp[0];
                *(uint4*)&As[buf][sr * 32 + sk + 8] = *(const uint4*)&tmp[8];
            } else {
                const short* ap = (const short*)A + (size_t)ar * K + k0 + sk;
                *(uint4*)&As[buf][sr * 32 + sk]     = *(const uint4*)(ap);
                *(uint4*)&As[buf][sr * 32 + sk + 8] = *(const uint4*)(ap + 8);
            }
            const short* bp = (const short*)Bt + (size_t)(bn + sr) * K + k0 + sk;
            *(uint4*)&Bs[buf][sr * 32 + sk]     = *(const uint4*)(bp);
            *(uint4*)&Bs[buf][sr * 32 + sk + 8] = *(const uint4*)(bp + 8);
        }
#endif
    };

    const int nt = K >> 5;
    stage(0, 0);
    __syncthreads();

    for (int t = 0; t < nt; ++t) {
        int cur = t & 1;
        if (t + 1 < nt) stage(cur ^ 1, (t + 1) * 32);

        short8 af[4], bg[4];
        #pragma unroll
        for (int m = 0; m < 4; ++m)
            af[m] = *(const short8*)&As[cur][(wm * 64 + m * 16 + fr) * 32 + fq * 8];
        #pragma unroll
        for (int n = 0; n < 4; ++n)
            bg[n] = *(const short8*)&Bs[cur][(wn * 64 + n * 16 + fr) * 32 + fq * 8];
        #pragma unroll
        for (int m = 0; m < 4; ++m)
            #pragma unroll
            for (int n = 0; n < 4; ++n)
                acc[m][n] = __builtin_amdgcn_mfma_f32_16x16x32_bf16(
                    af[m], bg[n], acc[m][n], 0, 0, 0);
        __syncthreads();
    }

    #pragma unroll
    for (int m = 0; m < 4; ++m) {
        #pragma unroll
        for (int n = 0; n < 4; ++n) {
            int col = bn + wn * 64 + n * 16 + fr;
            float bv = bias[col];
            #pragma unroll
            for (int r = 0; r < 4; ++r) {
                int row = bm + wm * 64 + m * 16 + fq * 4 + r;
                float v = acc[m][n][r] + bv;
                if (ACT == 1) v = fmaxf(v, 0.f);
                if (ACT == 2 && col >= 512) v = fmaxf(v, 0.f);
                stf(&C[(size_t)row * N + col], v);
            }
        }
    }
}

// ---------- prep: tiled transposes + ha/bkv tail ----------
__global__ __launch_bounds__(256) void prep_all_k(
    const float* __restrict__ W1, const float* __restrict__ Wq,
    const float* __restrict__ Wk, const float* __restrict__ Wv,
    const float* __restrict__ Wo, const float* __restrict__ h0,
    const float* __restrict__ bk, const float* __restrict__ bv,
    bf16* __restrict__ W1t, bf16* __restrict__ Wqt, bf16* __restrict__ Wkvt,
    bf16* __restrict__ Wot, _Float16* __restrict__ ha, float* __restrict__ bkv)
{
    int blk = blockIdx.x;
    int tid = threadIdx.x;
    if (blk < 848) {
        const float* src; bf16* dst; int K, N, ti;
        if (blk < 64)       { src = W1; dst = W1t;  K = 128; N = 512; ti = blk; }
        else if (blk < 320) { src = Wq; dst = Wqt;  K = 512; N = 512; ti = blk - 64; }
        else if (blk < 576) { src = Wk; dst = Wkvt; K = 512; N = 512; ti = blk - 320; }
        else if (blk < 832) { src = Wv; dst = Wkvt + 512 * 512; K = 512; N = 512; ti = blk - 576; }
        else                { src = Wo; dst = Wot;  K = 512; N = 32;  ti = blk - 832; }
        int kt = K >> 5;
        int tk = ti % kt, tn = ti / kt;
        int k0 = tk * 32, n0 = tn * 32;
        __shared__ float tile[32][33];
        int tx = tid & 31, ty = tid >> 5;
        #pragma unroll
        for (int i = 0; i < 4; ++i) {
            int r = ty + i * 8;
            tile[r][tx] = src[(size_t)(k0 + r) * N + n0 + tx];
        }
        __syncthreads();
        #pragma unroll
        for (int i = 0; i < 4; ++i) {
            int r = ty + i * 8;
            if (n0 + r < N)
                dst[(size_t)(n0 + r) * K + k0 + tx] = __float2bfloat16(tile[tx][r]);
        }
        return;
    }
    int idx = (blk - 848) * 256 + tid;
    if (idx < 131072) { ha[idx] = (_Float16)h0[idx]; return; }
    idx -= 131072;
    if (idx < 1024) { bkv[idx] = (idx < 512) ? bk[idx] : bv[idx - 512]; return; }
}

// ---------- qout MFMA ----------
__global__ __launch_bounds__(256) void qout_mfma_k(
    const float* __restrict__ hs, const bf16* __restrict__ Wot,
    const float* __restrict__ bo, const int* __restrict__ smask,
    float* __restrict__ out)
{
    __shared__ short Bs2[32 * 520];
    __shared__ short As2[128 * 32];
    const int tid = threadIdx.x;
    const int lane = tid & 63, wid = tid >> 6;
    const int bm = blockIdx.x * 128;
    const int fr = lane & 15, fq = lane >> 4;

    for (int i = tid; i < 2048; i += 256) {
        int row = i >> 6, col = (i & 63) * 8;
        *(uint4*)&Bs2[row * 520 + col] = *(const uint4*)((const short*)Wot + row * 512 + col);
    }

    f32x4 acc[2][2] = {};
    for (int k0 = 0; k0 < 512; k0 += 32) {
        {
            int sr = tid >> 1, sk = (tid & 1) * 16;
            const float* ap = hs + (size_t)(bm + sr) * 512 + k0 + sk;
            float4 f0 = *(const float4*)(ap);
            float4 f1 = *(const float4*)(ap + 4);
            float4 f2 = *(const float4*)(ap + 8);
            float4 f3 = *(const float4*)(ap + 12);
            short tmp[16] = {bfb(f0.x), bfb(f0.y), bfb(f0.z), bfb(f0.w),
                             bfb(f1.x), bfb(f1.y), bfb(f1.z), bfb(f1.w),
                             bfb(f2.x), bfb(f2.y), bfb(f2.z), bfb(f2.w),
                             bfb(f3.x), bfb(f3.y), bfb(f3.z), bfb(f3.w)};
            *(uint4*)&As2[sr * 32 + sk]     = *(const uint4*)&tmp[0];
            *(uint4*)&As2[sr * 32 + sk + 8] = *(const uint4*)&tmp[8];
        }
        __syncthreads();
        short8 af[2], bg[2];
        #pragma unroll
        for (int m = 0; m < 2; ++m)
            af[m] = *(const short8*)&As2[(wid * 32 + m * 16 + fr) * 32 + fq * 8];
        #pragma unroll
        for (int n = 0; n < 2; ++n)
            bg[n] = *(const short8*)&Bs2[(n * 16 + fr) * 520 + k0 + fq * 8];
        #pragma unroll
        for (int m = 0; m < 2; ++m)
            #pragma unroll
            for (int n = 0; n < 2; ++n)
                acc[m][n] = __builtin_amdgcn_mfma_f32_16x16x32_bf16(
                    af[m], bg[n], acc[m][n], 0, 0, 0);
        __syncthreads();
    }

    #pragma unroll
    for (int m = 0; m < 2; ++m) {
        #pragma unroll
        for (int n = 0; n < 2; ++n) {
            int col = n * 16 + fr;
            float bv = bo[col];
            #pragma unroll
            for (int r = 0; r < 4; ++r) {
                int row = bm + wid * 32 + m * 16 + fq * 4 + r;
                int a_ = row & 7, t_ = (row >> 3) & 63, b_ = row >> 9;
                bool mz = smask[((b_ << 6) + t_) * 32 + a_] != 0;
                out[(size_t)row * 32 + col] = mz ? 0.f : (acc[m][n][r] + bv);
            }
        }
    }
}

// ---------- attention: vectorized LDS (b128 reads), packed bf16 store ----------
#define AST 68
__global__ __launch_bounds__(64) void attn_k(
    const bf16* __restrict__ qb, const bf16* __restrict__ kb, const bf16* __restrict__ vb,
    const int* __restrict__ obs, const int* __restrict__ smask, bf16* __restrict__ xs,
    int kvstride)
{
    __shared__ float qs[8 * AST], ks[32 * AST], vs[32 * AST], wsm[8 * 33];
    int bid = blockIdx.x;
    int h = bid & 7;
    int bt = bid >> 3;
    int t = bt & 63, b = bt >> 6;
    int tid = threadIdx.x;

    {
        int srow = tid >> 3, c0 = (tid & 7) * 8;
        float4 lo, hi;
        uint4 qv = *(const uint4*)&qb[((size_t)bt * 8 + srow) * 512 + h * 64 + c0];
        unpack8(qv, lo, hi);
        *(float4*)&qs[srow * AST + c0] = lo;
        *(float4*)&qs[srow * AST + c0 + 4] = hi;
        #pragma unroll
        for (int i = 0; i < 4; ++i) {
            int row = srow + i * 8;
            uint4 kv4 = *(const uint4*)&kb[((size_t)bt * 32 + row) * kvstride + h * 64 + c0];
            unpack8(kv4, lo, hi);
            *(float4*)&ks[row * AST + c0] = lo;
            *(float4*)&ks[row * AST + c0 + 4] = hi;
            uint4 vv4 = *(const uint4*)&vb[((size_t)bt * 32 + row) * kvstride + h * 64 + c0];
            unpack8(vv4, lo, hi);
            *(float4*)&vs[row * AST + c0] = lo;
            *(float4*)&vs[row * AST + c0 + 4] = hi;
        }
    }
    __syncthreads();

    int ql = tid >> 3, jl = tid & 7;
    float s[4];
    #pragma unroll
    for (int c = 0; c < 4; ++c) {
        int kl = jl + c * 8;
        float4 a4 = make_float4(0.f, 0.f, 0.f, 0.f);
        #pragma unroll 4
        for (int d4 = 0; d4 < 16; ++d4) {
            float4 q4 = *(const float4*)&qs[ql * AST + d4 * 4];
            float4 k4 = *(const float4*)&ks[kl * AST + d4 * 4];
            a4.x += q4.x * k4.x; a4.y += q4.y * k4.y;
            a4.z += q4.z * k4.z; a4.w += q4.w * k4.w;
        }
        float acc = (a4.x + a4.y) + (a4.z + a4.w);
        acc *= 0.125f;
        bool m = obs[(((size_t)bt * 32) + ql) * 32 + kl] != 0;
        s[c] = m ? -__builtin_inff() : acc;
    }
    float mx = fmaxf(fmaxf(s[0], s[1]), fmaxf(s[2], s[3]));
    for (int off = 1; off < 8; off <<= 1) mx = fmaxf(mx, __shfl_xor(mx, off));
    float e4[4]; float sum = 0.f;
    bool allmasked = (mx == -__builtin_inff());
    #pragma unroll
    for (int c = 0; c < 4; ++c) {
        e4[c] = (allmasked || s[c] == -__builtin_inff()) ? 0.f : expf(s[c] - mx);
        sum += e4[c];
    }
    for (int off = 1; off < 8; off <<= 1) sum += __shfl_xor(sum, off);
    float inv = (sum > 0.f) ? 1.f / sum : 0.f;
    #pragma unroll
    for (int c = 0; c < 4; ++c) wsm[ql * 33 + jl + c * 8] = e4[c] * inv;
    __syncthreads();

    bool amask = smask[(size_t)bt * 32 + ql] != 0;
    int d0 = jl * 8;
    float4 o0 = make_float4(0.f, 0.f, 0.f, 0.f);
    float4 o1 = make_float4(0.f, 0.f, 0.f, 0.f);
    #pragma unroll 4
    for (int kl = 0; kl < 32; ++kl) {
        float w = wsm[ql * 33 + kl];
        float4 v0 = *(const float4*)&vs[kl * AST + d0];
        float4 v1 = *(const float4*)&vs[kl * AST + d0 + 4];
        o0.x += w * v0.x; o0.y += w * v0.y; o0.z += w * v0.z; o0.w += w * v0.w;
        o1.x += w * v1.x; o1.y += w * v1.y; o1.z += w * v1.z; o1.w += w * v1.w;
    }
    if (amask) { o0 = make_float4(0.f, 0.f, 0.f, 0.f); o1 = o0; }
    uint4 pk;
    pk.x = pk2(o0.x, o0.y); pk.y = pk2(o0.z, o0.w);
    pk.z = pk2(o1.x, o1.y); pk.w = pk2(o1.z, o1.w);
    *(uint4*)&xs[((size_t)(t * 256 + b * 8 + ql)) * 512 + h * 64 + d0] = pk;
}

// ---------- GRU v11b: producer/consumer waves (prologue race FIXED) ----------
// 256 WGs x 256 thr (4 waves). Waves 0-1: recurrence; waves 2-3: gi(t+1) into
// gbuf double-buffer. FIX vs r18: __syncthreads after w-staging, BEFORE
// gi_pass(0) — gi_pass reads ALL of wi16, which other waves stage.
__global__ __launch_bounds__(256, 1) void gru_xcd_k(
    const bf16* __restrict__ xs, const float* __restrict__ Wih,
    const float* __restrict__ bih,
    const float* __restrict__ Whh, const float* __restrict__ bhh,
    const float* __restrict__ h0,
    const int* __restrict__ smask, float* __restrict__ hs_out,
    _Float16* __restrict__ ha, _Float16* __restrict__ hb, int* __restrict__ flags)
{
    __shared__ _Float16 wh16[48 * 520];     // Whh slice (f16)
    __shared__ short    wi16[48 * 520];     // Wih slice (bf16)
    __shared__ float    gbuf[2][32][49];    // gi double-buffer
    const int tid = threadIdx.x;
    const int lane = tid & 63, wid = tid >> 6;
    const int g = blockIdx.x;
    const int grp = g & 7, cu = g >> 3;
    const int r0 = grp * 32;
    const int hc0 = cu * 16;
    const int fr = lane & 15, fq = lane >> 4;
    const int hcol = hc0 + fr;

    for (int i = tid; i < 6144; i += 256) {
        int flat = i * 4;
        int r = flat >> 9, c = flat & 511;
        int wr = (r >> 4) * 512 + hc0 + (r & 15);
        float4 v = *(const float4*)(Whh + (size_t)wr * 512 + c);
        half2v p0; p0[0] = (_Float16)v.x; p0[1] = (_Float16)v.y;
        half2v p1; p1[0] = (_Float16)v.z; p1[1] = (_Float16)v.w;
        *(uint32_t*)&wh16[r * 520 + c]     = __builtin_bit_cast(uint32_t, p0);
        *(uint32_t*)&wh16[r * 520 + c + 2] = __builtin_bit_cast(uint32_t, p1);
        float4 u = *(const float4*)(Wih + (size_t)wr * 512 + c);
        uint32_t w0 = (uint32_t)(uint16_t)bfb(u.x) | ((uint32_t)(uint16_t)bfb(u.y) << 16);
        uint32_t w1 = (uint32_t)(uint16_t)bfb(u.z) | ((uint32_t)(uint16_t)bfb(u.w) << 16);
        *(uint32_t*)&wi16[r * 520 + c]     = w0;
        *(uint32_t*)&wi16[r * 520 + c + 2] = w1;
    }
    __syncthreads();   // *** FIX: wi16/wh16 fully staged before ANY reader ***

    auto gi_pass = [&](int tt, int buf) {
        const int wrow = (wid - 2) * 16;
        const short* xp = (const short*)xs + ((size_t)tt * 256 + r0 + wrow + fr) * 512 + fq * 8;
        short8 ax[16];
        #pragma unroll
        for (int ks = 0; ks < 16; ++ks) ax[ks] = *(const short8*)(xp + ks * 32);
        f32x4 gg[3] = {};
        #pragma unroll
        for (int ks = 0; ks < 16; ++ks) {
            const short* bb = &wi16[fr * 520 + ks * 32 + fq * 8];
            short8 b0 = *(const short8*)(bb);
            short8 b1 = *(const short8*)(bb + 16 * 520);
            short8 b2 = *(const short8*)(bb + 32 * 520);
            gg[0] = __builtin_amdgcn_mfma_f32_16x16x32_bf16(ax[ks], b0, gg[0], 0, 0, 0);
            gg[1] = __builtin_amdgcn_mfma_f32_16x16x32_bf16(ax[ks], b1, gg[1], 0, 0, 0);
            gg[2] = __builtin_amdgcn_mfma_f32_16x16x32_bf16(ax[ks], b2, gg[2], 0, 0, 0);
        }
        #pragma unroll
        for (int gg_i = 0; gg_i < 3; ++gg_i)
            #pragma unroll
            for (int r = 0; r < 4; ++r)
                gbuf[buf][wrow + fq * 4 + r][gg_i * 16 + fr] = gg[gg_i][r];
    };

    const int rw0 = r0 + (wid & 1) * 16;
    const int row0 = rw0 + fq * 4;
    const int lrow = (wid & 1) * 16 + fq * 4;
    float bhr = 0, bhz = 0, bhn = 0, bir = 0, biz = 0, bin_ = 0;
    float hp[4];
    int mcur[4];
    if (wid < 2) {
        bhr = bhh[hcol]; bhz = bhh[512 + hcol]; bhn = bhh[1024 + hcol];
        bir = bih[hcol]; biz = bih[512 + hcol]; bin_ = bih[1024 + hcol];
        #pragma unroll
        for (int r = 0; r < 4; ++r)
            hp[r] = h0[(size_t)(row0 + r) * 512 + hcol];
        #pragma unroll
        for (int r = 0; r < 4; ++r) {
            int row = row0 + r;
            mcur[r] = smask[(((row >> 3) << 6) + 0) * 32 + (row & 7)];
        }
    } else {
        gi_pass(0, 0);
    }
    __syncthreads();        // gbuf[0] staged

    for (int t = 0; t < 64; ++t) {
        if (wid < 2) {
            const _Float16* hsrc = (t & 1) ? hb : ha;
            _Float16*       hdst = (t & 1) ? ha : hb;

            half8 aA[16];
            {
                const unsigned long long* ap = (const unsigned long long*)
                    (hsrc + (size_t)(rw0 + fr) * 512 + fq * 8);
                #pragma unroll
                for (int ks = 0; ks < 16; ++ks) {
                    unsigned long long lo = __hip_atomic_load(ap + ks * 8,
                        __ATOMIC_RELAXED, __HIP_MEMORY_SCOPE_AGENT);
                    unsigned long long hi = __hip_atomic_load(ap + ks * 8 + 1,
                        __ATOMIC_RELAXED, __HIP_MEMORY_SCOPE_AGENT);
                    aA[ks] = h8_from(lo, hi);
                }
            }

            f32x4 acc[3] = {};
            #pragma unroll
            for (int ks = 0; ks < 16; ++ks) {
                const _Float16* bbase = &wh16[fr * 520 + ks * 32 + fq * 8];
                half8 b0 = *(const half8*)(bbase);
                half8 b1 = *(const half8*)(bbase + 16 * 520);
                half8 b2 = *(const half8*)(bbase + 32 * 520);
                acc[0] = __builtin_amdgcn_mfma_f32_16x16x32_f16(aA[ks], b0, acc[0], 0, 0, 0);
                acc[1] = __builtin_amdgcn_mfma_f32_16x16x32_f16(aA[ks], b1, acc[1], 0, 0, 0);
                acc[2] = __builtin_amdgcn_mfma_f32_16x16x32_f16(aA[ks], b2, acc[2], 0, 0, 0);
            }

            float hnv[4];
            #pragma unroll
            for (int r = 0; r < 4; ++r) {
                float gr_ = gbuf[t & 1][lrow + r][fr];
                float gz_ = gbuf[t & 1][lrow + r][16 + fr];
                float gn_ = gbuf[t & 1][lrow + r][32 + fr];
                float rg = fsig(gr_ + bir + acc[0][r] + bhr);
                float zg = fsig(gz_ + biz + acc[1][r] + bhz);
                float ng = ftanh(gn_ + bin_ + rg * (acc[2][r] + bhn));
                float hn = (1.f - zg) * ng + zg * hp[r];
                hp[r] = hn;
                hnv[r] = hn;
                unsigned short hbits = __builtin_bit_cast(unsigned short, (_Float16)hn);
                __hip_atomic_store((unsigned short*)(hdst + (size_t)(row0 + r) * 512 + hcol),
                                   hbits, __ATOMIC_RELAXED, __HIP_MEMORY_SCOPE_AGENT);
            }

            if (t != 63) {
                asm volatile("s_waitcnt vmcnt(0)" ::: "memory");
                __builtin_amdgcn_sched_barrier(0);
                if (lane == 0)
                    __hip_atomic_store(flags + ((size_t)grp * 64 + t) * 64 + cu * 2 + wid, 1,
                                       __ATOMIC_RELAXED, __HIP_MEMORY_SCOPE_AGENT);
            }
            #pragma unroll
            for (int r = 0; r < 4; ++r) {
                int row = row0 + r;
                int b_ = row >> 3, a_ = row & 7;
                hs_out[((size_t)((b_ << 6) + t) * 8 + a_) * 512 + hcol] =
                    mcur[r] ? 0.f : hnv[r];
            }
            if (t != 63) {
                #pragma unroll
                for (int r = 0; r < 4; ++r) {
                    int row = row0 + r;
                    mcur[r] = smask[(((row >> 3) << 6) + (t + 1)) * 32 + (row & 7)];
                }
            }
        } else {
            if (t < 63) gi_pass(t + 1, (t + 1) & 1);
        }

        __syncthreads();    // gbuf[(t+1)&1] ready; compute past gates(t)

        if (wid < 2 && t != 63) {
            const int* fp = flags + ((size_t)grp * 64 + t) * 64 + lane;
            long it = 0;
            for (;;) {
                int f = __hip_atomic_load(fp, __ATOMIC_RELAXED, __HIP_MEMORY_SCOPE_AGENT);
                if (__all(f != 0) || it > 100000000L) break;
                __builtin_amdgcn_s_sleep(1);
                ++it;
            }
            __builtin_amdgcn_sched_barrier(0);
        }
    }
}

// ---------- launch ----------
extern "C" void kernel_launch(void* const* d_in, const int* in_sizes, int n_in,
                              void* d_out, int out_size, void* d_ws, size_t ws_size,
                              hipStream_t stream)
{
    const float* inputs = (const float*)d_in[0];
    const int*   obs    = (const int*)d_in[1];
    const int*   smask  = (const int*)d_in[2];
    const float* h0     = (const float*)d_in[3];
    const float* W1  = (const float*)d_in[4];  const float* b1  = (const float*)d_in[5];
    const float* Wq  = (const float*)d_in[6];  const float* bq  = (const float*)d_in[7];
    const float* Wk  = (const float*)d_in[8];  const float* bk  = (const float*)d_in[9];
    const float* Wv  = (const float*)d_in[10]; const float* bv  = (const float*)d_in[11];
    const float* Wih = (const float*)d_in[12]; const float* bih = (const float*)d_in[13];
    const float* Whh = (const float*)d_in[14]; const float* bhh = (const float*)d_in[15];
    const float* Wo  = (const float*)d_in[16]; const float* bo  = (const float*)d_in[17];

    char* ws = (char*)d_ws;
    bf16*  x    = (bf16*)(ws + 0);
    bf16*  xs   = (bf16*)(ws + 0);
    bf16*  qb   = (bf16*)(ws + 67108864ull);
    bf16*  kv   = (bf16*)(ws + 83886080ull);
    bf16*  W1t  = (bf16*)(ws + 218103808ull);
    bf16*  Wqt  = (bf16*)(ws + 218234880ull);
    bf16*  Wkvt = (bf16*)(ws + 218759168ull);
    _Float16* ha = (_Float16*)(ws + 219807744ull);
    _Float16* hb = (_Float16*)(ws + 220069888ull);
    int*   flags = (int*)(ws + 220332032ull);
    float* bkv  = (float*)(ws + 220463104ull);
    bf16*  Wot  = (bf16*)(ws + 220467200ull);

    float* out    = (float*)d_out;
    float* hs_out = out + 524288;

    hipMemsetAsync(flags, 0, 131072, stream);

    prep_all_k<<<dim3(1365), 256, 0, stream>>>(
        W1, Wq, Wk, Wv, Wo, h0, bk, bv, W1t, Wqt, Wkvt, Wot, ha, bkv);
    mfma_gemm_k<1, false, float, bf16><<<dim3(4, 512), 256, 0, stream>>>(
        inputs, W1t, b1, x, 65536, 512, 128);
    mfma_gemm_k<0, true, bf16, bf16><<<dim3(4, 128), 256, 0, stream>>>(
        x, Wqt, bq, qb, 16384, 512, 512);
    mfma_gemm_k<2, false, bf16, bf16><<<dim3(8, 512), 256, 0, stream>>>(
        x, Wkvt, bkv, kv, 65536, 1024, 512);
    attn_k<<<dim3(16384), 64, 0, stream>>>(qb, kv, kv + 512, obs, smask, xs, 1024);
    gru_xcd_k<<<dim3(256), 256, 0, stream>>>(
        xs, Wih, bih, Whh, bhh, h0, smask, hs_out, ha, hb, flags);
    qout_mfma_k<<<dim3(128), 256, 0, stream>>>(hs_out, Wot, bo, smask, out);
}

// Round 20
// 536.141 us; speedup vs baseline: 1.0361x; 1.0361x over previous
//
#include <hip/hip_runtime.h>
#include <hip/hip_bf16.h>
#include <cstddef>
#include <cstdint>

typedef __hip_bfloat16 bf16;
typedef __attribute__((ext_vector_type(2))) _Float16 half2v;
typedef __attribute__((ext_vector_type(8))) _Float16 half8;
typedef __attribute__((ext_vector_type(8))) short short8;
typedef __attribute__((ext_vector_type(4))) float f32x4;
typedef __attribute__((ext_vector_type(2))) unsigned long long u64x2;

// ---------- helpers ----------
__device__ inline float ldf(const float* p) { return *p; }
__device__ inline float ldf(const bf16* p) { return __bfloat162float(*p); }
__device__ inline void stf(float* p, float v) { *p = v; }
__device__ inline void stf(bf16* p, float v) { *p = __float2bfloat16(v); }
__device__ inline short bfb(float v) { return __builtin_bit_cast(short, __float2bfloat16(v)); }

__device__ inline half8 h8_from(unsigned long long lo, unsigned long long hi) {
    u64x2 t; t.x = lo; t.y = hi;
    return __builtin_bit_cast(half8, t);
}
__device__ inline float fsig(float x) {
    x = fminf(fmaxf(x, -60.f), 60.f);
    return 1.f / (1.f + __expf(-x));
}
__device__ inline float ftanh(float x) {
    x = fminf(fmaxf(x, -15.f), 15.f);
    float e = __expf(2.f * x);
    return 1.f - 2.f / (e + 1.f);
}
__device__ inline void unpack8(uint4 u, float4& lo, float4& hi) {
    uint32_t w0 = u.x, w1 = u.y, w2 = u.z, w3 = u.w;
    lo.x = __builtin_bit_cast(float, (w0 & 0xffffu) << 16);
    lo.y = __builtin_bit_cast(float, w0 & 0xffff0000u);
    lo.z = __builtin_bit_cast(float, (w1 & 0xffffu) << 16);
    lo.w = __builtin_bit_cast(float, w1 & 0xffff0000u);
    hi.x = __builtin_bit_cast(float, (w2 & 0xffffu) << 16);
    hi.y = __builtin_bit_cast(float, w2 & 0xffff0000u);
    hi.z = __builtin_bit_cast(float, (w3 & 0xffffu) << 16);
    hi.w = __builtin_bit_cast(float, w3 & 0xffff0000u);
}
__device__ inline uint32_t pk2(float a, float b) {
    return ((uint32_t)(uint16_t)bfb(a)) | (((uint32_t)(uint16_t)bfb(b)) << 16);
}

// Problem constants: BS=32, T=64, NE=32, NA=8, ED=128, H=512, A=512, NH=8, HD=64, NACT=32

// ---------- MFMA bf16 GEMM, 2-phase double-buffered staging ----------
template<int ACT, bool QG, typename TA, typename TC>
__global__ __launch_bounds__(256) void mfma_gemm_k(
    const TA* __restrict__ A, const bf16* __restrict__ Bt,
    const float* __restrict__ bias, TC* __restrict__ C,
    int M, int N, int K)
{
    __shared__ short As[2][4096];
    __shared__ short Bs[2][4096];
    const int tid = threadIdx.x;
    const int lane = tid & 63, wid = tid >> 6;
    const int wm = wid >> 1, wn = wid & 1;
    const int bm = blockIdx.y * 128, bn = blockIdx.x * 128;
    const int fr = lane & 15, fq = lane >> 4;

    f32x4 acc[4][4] = {};

    auto stage = [&](int buf, int k0) {
#if __has_builtin(__builtin_amdgcn_global_load_lds)
        #pragma unroll
        for (int j = 0; j < 2; ++j) {
            int jj = wid * 2 + j;
            int row = jj * 16 + (lane >> 2);
            const short* src = (const short*)Bt + (size_t)(bn + row) * K + k0 + (lane & 3) * 8;
            __builtin_amdgcn_global_load_lds(
                (const __attribute__((address_space(1))) void*)src,
                (__attribute__((address_space(3))) void*)&Bs[buf][jj * 512], 16, 0, 0);
        }
        if constexpr (sizeof(TA) == 2) {
            #pragma unroll
            for (int j = 0; j < 2; ++j) {
                int jj = wid * 2 + j;
                int row = jj * 16 + (lane >> 2);
                int gm = bm + row;
                int ar = QG ? (((gm >> 3) << 5) | (gm & 7)) : gm;
                const short* src = (const short*)A + (size_t)ar * K + k0 + (lane & 3) * 8;
                __builtin_amdgcn_global_load_lds(
                    (const __attribute__((address_space(1))) void*)src,
                    (__attribute__((address_space(3))) void*)&As[buf][jj * 512], 16, 0, 0);
            }
        } else {
            int sr = tid >> 1, sk = (tid & 1) * 16;
            int gm = bm + sr;
            int ar = QG ? (((gm >> 3) << 5) | (gm & 7)) : gm;
            const float* ap = (const float*)A + (size_t)ar * K + k0 + sk;
            float4 f0 = *(const float4*)(ap);
            float4 f1 = *(const float4*)(ap + 4);
            float4 f2 = *(const float4*)(ap + 8);
            float4 f3 = *(const float4*)(ap + 12);
            short tmp[16] = {bfb(f0.x), bfb(f0.y), bfb(f0.z), bfb(f0.w),
                             bfb(f1.x), bfb(f1.y), bfb(f1.z), bfb(f1.w),
                             bfb(f2.x), bfb(f2.y), bfb(f2.z), bfb(f2.w),
                             bfb(f3.x), bfb(f3.y), bfb(f3.z), bfb(f3.w)};
            *(uint4*)&As[buf][sr * 32 + sk]     = *(const uint4*)&tmp[0];
            *(uint4*)&As[buf][sr * 32 + sk + 8] = *(const uint4*)&tmp[8];
        }
#else
        {
            int sr = tid >> 1, sk = (tid & 1) * 16;
            int gm = bm + sr;
            int ar = QG ? (((gm >> 3) << 5) | (gm & 7)) : gm;
            if constexpr (sizeof(TA) == 4) {
                const float* ap = (const float*)A + (size_t)ar * K + k0 + sk;
                short tmp[16];
                #pragma unroll
                for (int j = 0; j < 16; ++j) tmp[j] = bfb(ap[j]);
                *(uint4*)&As[buf][sr * 32 + sk]     = *(const uint4*)&tmp[0];
                *(uint4*)&As[buf][sr * 32 + sk + 8] = *(const uint4*)&tmp[8];
            } else {
                const short* ap = (const short*)A + (size_t)ar * K + k0 + sk;
                *(uint4*)&As[buf][sr * 32 + sk]     = *(const uint4*)(ap);
                *(uint4*)&As[buf][sr * 32 + sk + 8] = *(const uint4*)(ap + 8);
            }
            const short* bp = (const short*)Bt + (size_t)(bn + sr) * K + k0 + sk;
            *(uint4*)&Bs[buf][sr * 32 + sk]     = *(const uint4*)(bp);
            *(uint4*)&Bs[buf][sr * 32 + sk + 8] = *(const uint4*)(bp + 8);
        }
#endif
    };

    const int nt = K >> 5;
    stage(0, 0);
    __syncthreads();

    for (int t = 0; t < nt; ++t) {
        int cur = t & 1;
        if (t + 1 < nt) stage(cur ^ 1, (t + 1) * 32);

        short8 af[4], bg[4];
        #pragma unroll
        for (int m = 0; m < 4; ++m)
            af[m] = *(const short8*)&As[cur][(wm * 64 + m * 16 + fr) * 32 + fq * 8];
        #pragma unroll
        for (int n = 0; n < 4; ++n)
            bg[n] = *(const short8*)&Bs[cur][(wn * 64 + n * 16 + fr) * 32 + fq * 8];
        #pragma unroll
        for (int m = 0; m < 4; ++m)
            #pragma unroll
            for (int n = 0; n < 4; ++n)
                acc[m][n] = __builtin_amdgcn_mfma_f32_16x16x32_bf16(
                    af[m], bg[n], acc[m][n], 0, 0, 0);
        __syncthreads();
    }

    #pragma unroll
    for (int m = 0; m < 4; ++m) {
        #pragma unroll
        for (int n = 0; n < 4; ++n) {
            int col = bn + wn * 64 + n * 16 + fr;
            float bv = bias[col];
            #pragma unroll
            for (int r = 0; r < 4; ++r) {
                int row = bm + wm * 64 + m * 16 + fq * 4 + r;
                float v = acc[m][n][r] + bv;
                if (ACT == 1) v = fmaxf(v, 0.f);
                if (ACT == 2 && col >= 512) v = fmaxf(v, 0.f);
                stf(&C[(size_t)row * N + col], v);
            }
        }
    }
}

// ---------- prep: tiled transposes + ha/bkv tail ----------
__global__ __launch_bounds__(256) void prep_all_k(
    const float* __restrict__ W1, const float* __restrict__ Wq,
    const float* __restrict__ Wk, const float* __restrict__ Wv,
    const float* __restrict__ Wo, const float* __restrict__ h0,
    const float* __restrict__ bk, const float* __restrict__ bv,
    bf16* __restrict__ W1t, bf16* __restrict__ Wqt, bf16* __restrict__ Wkvt,
    bf16* __restrict__ Wot, _Float16* __restrict__ ha, float* __restrict__ bkv)
{
    int blk = blockIdx.x;
    int tid = threadIdx.x;
    if (blk < 848) {
        const float* src; bf16* dst; int K, N, ti;
        if (blk < 64)       { src = W1; dst = W1t;  K = 128; N = 512; ti = blk; }
        else if (blk < 320) { src = Wq; dst = Wqt;  K = 512; N = 512; ti = blk - 64; }
        else if (blk < 576) { src = Wk; dst = Wkvt; K = 512; N = 512; ti = blk - 320; }
        else if (blk < 832) { src = Wv; dst = Wkvt + 512 * 512; K = 512; N = 512; ti = blk - 576; }
        else                { src = Wo; dst = Wot;  K = 512; N = 32;  ti = blk - 832; }
        int kt = K >> 5;
        int tk = ti % kt, tn = ti / kt;
        int k0 = tk * 32, n0 = tn * 32;
        __shared__ float tile[32][33];
        int tx = tid & 31, ty = tid >> 5;
        #pragma unroll
        for (int i = 0; i < 4; ++i) {
            int r = ty + i * 8;
            tile[r][tx] = src[(size_t)(k0 + r) * N + n0 + tx];
        }
        __syncthreads();
        #pragma unroll
        for (int i = 0; i < 4; ++i) {
            int r = ty + i * 8;
            if (n0 + r < N)
                dst[(size_t)(n0 + r) * K + k0 + tx] = __float2bfloat16(tile[tx][r]);
        }
        return;
    }
    int idx = (blk - 848) * 256 + tid;
    if (idx < 131072) { ha[idx] = (_Float16)h0[idx]; return; }
    idx -= 131072;
    if (idx < 1024) { bkv[idx] = (idx < 512) ? bk[idx] : bv[idx - 512]; return; }
}

// ---------- qout MFMA ----------
__global__ __launch_bounds__(256) void qout_mfma_k(
    const float* __restrict__ hs, const bf16* __restrict__ Wot,
    const float* __restrict__ bo, const int* __restrict__ smask,
    float* __restrict__ out)
{
    __shared__ short Bs2[32 * 520];
    __shared__ short As2[128 * 32];
    const int tid = threadIdx.x;
    const int lane = tid & 63, wid = tid >> 6;
    const int bm = blockIdx.x * 128;
    const int fr = lane & 15, fq = lane >> 4;

    for (int i = tid; i < 2048; i += 256) {
        int row = i >> 6, col = (i & 63) * 8;
        *(uint4*)&Bs2[row * 520 + col] = *(const uint4*)((const short*)Wot + row * 512 + col);
    }

    f32x4 acc[2][2] = {};
    for (int k0 = 0; k0 < 512; k0 += 32) {
        {
            int sr = tid >> 1, sk = (tid & 1) * 16;
            const float* ap = hs + (size_t)(bm + sr) * 512 + k0 + sk;
            float4 f0 = *(const float4*)(ap);
            float4 f1 = *(const float4*)(ap + 4);
            float4 f2 = *(const float4*)(ap + 8);
            float4 f3 = *(const float4*)(ap + 12);
            short tmp[16] = {bfb(f0.x), bfb(f0.y), bfb(f0.z), bfb(f0.w),
                             bfb(f1.x), bfb(f1.y), bfb(f1.z), bfb(f1.w),
                             bfb(f2.x), bfb(f2.y), bfb(f2.z), bfb(f2.w),
                             bfb(f3.x), bfb(f3.y), bfb(f3.z), bfb(f3.w)};
            *(uint4*)&As2[sr * 32 + sk]     = *(const uint4*)&tmp[0];
            *(uint4*)&As2[sr * 32 + sk + 8] = *(const uint4*)&tmp[8];
        }
        __syncthreads();
        short8 af[2], bg[2];
        #pragma unroll
        for (int m = 0; m < 2; ++m)
            af[m] = *(const short8*)&As2[(wid * 32 + m * 16 + fr) * 32 + fq * 8];
        #pragma unroll
        for (int n = 0; n < 2; ++n)
            bg[n] = *(const short8*)&Bs2[(n * 16 + fr) * 520 + k0 + fq * 8];
        #pragma unroll
        for (int m = 0; m < 2; ++m)
            #pragma unroll
            for (int n = 0; n < 2; ++n)
                acc[m][n] = __builtin_amdgcn_mfma_f32_16x16x32_bf16(
                    af[m], bg[n], acc[m][n], 0, 0, 0);
        __syncthreads();
    }

    #pragma unroll
    for (int m = 0; m < 2; ++m) {
        #pragma unroll
        for (int n = 0; n < 2; ++n) {
            int col = n * 16 + fr;
            float bv = bo[col];
            #pragma unroll
            for (int r = 0; r < 4; ++r) {
                int row = bm + wid * 32 + m * 16 + fq * 4 + r;
                int a_ = row & 7, t_ = (row >> 3) & 63, b_ = row >> 9;
                bool mz = smask[((b_ << 6) + t_) * 32 + a_] != 0;
                out[(size_t)row * 32 + col] = mz ? 0.f : (acc[m][n][r] + bv);
            }
        }
    }
}

// ---------- attention: vectorized LDS (b128 reads), packed bf16 store ----------
#define AST 68
__global__ __launch_bounds__(64) void attn_k(
    const bf16* __restrict__ qb, const bf16* __restrict__ kb, const bf16* __restrict__ vb,
    const int* __restrict__ obs, const int* __restrict__ smask, bf16* __restrict__ xs,
    int kvstride)
{
    __shared__ float qs[8 * AST], ks[32 * AST], vs[32 * AST], wsm[8 * 33];
    int bid = blockIdx.x;
    int h = bid & 7;
    int bt = bid >> 3;
    int t = bt & 63, b = bt >> 6;
    int tid = threadIdx.x;

    {
        int srow = tid >> 3, c0 = (tid & 7) * 8;
        float4 lo, hi;
        uint4 qv = *(const uint4*)&qb[((size_t)bt * 8 + srow) * 512 + h * 64 + c0];
        unpack8(qv, lo, hi);
        *(float4*)&qs[srow * AST + c0] = lo;
        *(float4*)&qs[srow * AST + c0 + 4] = hi;
        #pragma unroll
        for (int i = 0; i < 4; ++i) {
            int row = srow + i * 8;
            uint4 kv4 = *(const uint4*)&kb[((size_t)bt * 32 + row) * kvstride + h * 64 + c0];
            unpack8(kv4, lo, hi);
            *(float4*)&ks[row * AST + c0] = lo;
            *(float4*)&ks[row * AST + c0 + 4] = hi;
            uint4 vv4 = *(const uint4*)&vb[((size_t)bt * 32 + row) * kvstride + h * 64 + c0];
            unpack8(vv4, lo, hi);
            *(float4*)&vs[row * AST + c0] = lo;
            *(float4*)&vs[row * AST + c0 + 4] = hi;
        }
    }
    __syncthreads();

    int ql = tid >> 3, jl = tid & 7;
    float s[4];
    #pragma unroll
    for (int c = 0; c < 4; ++c) {
        int kl = jl + c * 8;
        float4 a4 = make_float4(0.f, 0.f, 0.f, 0.f);
        #pragma unroll 4
        for (int d4 = 0; d4 < 16; ++d4) {
            float4 q4 = *(const float4*)&qs[ql * AST + d4 * 4];
            float4 k4 = *(const float4*)&ks[kl * AST + d4 * 4];
            a4.x += q4.x * k4.x; a4.y += q4.y * k4.y;
            a4.z += q4.z * k4.z; a4.w += q4.w * k4.w;
        }
        float acc = (a4.x + a4.y) + (a4.z + a4.w);
        acc *= 0.125f;
        bool m = obs[(((size_t)bt * 32) + ql) * 32 + kl] != 0;
        s[c] = m ? -__builtin_inff() : acc;
    }
    float mx = fmaxf(fmaxf(s[0], s[1]), fmaxf(s[2], s[3]));
    for (int off = 1; off < 8; off <<= 1) mx = fmaxf(mx, __shfl_xor(mx, off));
    float e4[4]; float sum = 0.f;
    bool allmasked = (mx == -__builtin_inff());
    #pragma unroll
    for (int c = 0; c < 4; ++c) {
        e4[c] = (allmasked || s[c] == -__builtin_inff()) ? 0.f : expf(s[c] - mx);
        sum += e4[c];
    }
    for (int off = 1; off < 8; off <<= 1) sum += __shfl_xor(sum, off);
    float inv = (sum > 0.f) ? 1.f / sum : 0.f;
    #pragma unroll
    for (int c = 0; c < 4; ++c) wsm[ql * 33 + jl + c * 8] = e4[c] * inv;
    __syncthreads();

    bool amask = smask[(size_t)bt * 32 + ql] != 0;
    int d0 = jl * 8;
    float4 o0 = make_float4(0.f, 0.f, 0.f, 0.f);
    float4 o1 = make_float4(0.f, 0.f, 0.f, 0.f);
    #pragma unroll 4
    for (int kl = 0; kl < 32; ++kl) {
        float w = wsm[ql * 33 + kl];
        float4 v0 = *(const float4*)&vs[kl * AST + d0];
        float4 v1 = *(const float4*)&vs[kl * AST + d0 + 4];
        o0.x += w * v0.x; o0.y += w * v0.y; o0.z += w * v0.z; o0.w += w * v0.w;
        o1.x += w * v1.x; o1.y += w * v1.y; o1.z += w * v1.z; o1.w += w * v1.w;
    }
    if (amask) { o0 = make_float4(0.f, 0.f, 0.f, 0.f); o1 = o0; }
    uint4 pk;
    pk.x = pk2(o0.x, o0.y); pk.y = pk2(o0.z, o0.w);
    pk.z = pk2(o1.x, o1.y); pk.w = pk2(o1.z, o1.w);
    *(uint4*)&xs[((size_t)(t * 256 + b * 8 + ql)) * 512 + h * 64 + d0] = pk;
}

// ---------- GRU (r17 proven optimum): 2 waves/WG, gi in poll shadow,
// per-wave int flags + s_sleep poll ----------
__global__ __launch_bounds__(128, 1) void gru_xcd_k(
    const bf16* __restrict__ xs, const float* __restrict__ Wih,
    const float* __restrict__ bih,
    const float* __restrict__ Whh, const float* __restrict__ bhh,
    const float* __restrict__ h0,
    const int* __restrict__ smask, float* __restrict__ hs_out,
    _Float16* __restrict__ ha, _Float16* __restrict__ hb, int* __restrict__ flags)
{
    __shared__ _Float16 wh16[48 * 520];
    __shared__ short    wi16[48 * 520];
    const int tid = threadIdx.x;
    const int lane = tid & 63, wid = tid >> 6;
    const int g = blockIdx.x;
    const int grp = g & 7, cu = g >> 3;
    const int r0 = grp * 32;
    const int hc0 = cu * 16;
    const int fr = lane & 15, fq = lane >> 4;
    const int hcol = hc0 + fr;
    const int rw0 = r0 + wid * 16;
    const int row0 = rw0 + fq * 4;

    for (int i = tid; i < 6144; i += 128) {
        int flat = i * 4;
        int r = flat >> 9, c = flat & 511;
        int wr = (r >> 4) * 512 + hc0 + (r & 15);
        float4 v = *(const float4*)(Whh + (size_t)wr * 512 + c);
        half2v p0; p0[0] = (_Float16)v.x; p0[1] = (_Float16)v.y;
        half2v p1; p1[0] = (_Float16)v.z; p1[1] = (_Float16)v.w;
        *(uint32_t*)&wh16[r * 520 + c]     = __builtin_bit_cast(uint32_t, p0);
        *(uint32_t*)&wh16[r * 520 + c + 2] = __builtin_bit_cast(uint32_t, p1);
        float4 u = *(const float4*)(Wih + (size_t)wr * 512 + c);
        uint32_t w0 = (uint32_t)(uint16_t)bfb(u.x) | ((uint32_t)(uint16_t)bfb(u.y) << 16);
        uint32_t w1 = (uint32_t)(uint16_t)bfb(u.z) | ((uint32_t)(uint16_t)bfb(u.w) << 16);
        *(uint32_t*)&wi16[r * 520 + c]     = w0;
        *(uint32_t*)&wi16[r * 520 + c + 2] = w1;
    }

    const float bhr = bhh[hcol], bhz = bhh[512 + hcol], bhn = bhh[1024 + hcol];
    const float bir = bih[hcol], biz = bih[512 + hcol], bin_ = bih[1024 + hcol];

    float hp[4];
    #pragma unroll
    for (int r = 0; r < 4; ++r)
        hp[r] = h0[(size_t)(row0 + r) * 512 + hcol];

    __syncthreads();

    f32x4 gcur[3] = {};
    int mcur[4];
    {
        const short* xp = (const short*)xs + ((size_t)0 * 256 + rw0 + fr) * 512 + fq * 8;
        short8 ax[16];
        #pragma unroll
        for (int ks = 0; ks < 16; ++ks) ax[ks] = *(const short8*)(xp + ks * 32);
        #pragma unroll
        for (int ks = 0; ks < 16; ++ks) {
            const short* bb = &wi16[fr * 520 + ks * 32 + fq * 8];
            short8 b0 = *(const short8*)(bb);
            short8 b1 = *(const short8*)(bb + 16 * 520);
            short8 b2 = *(const short8*)(bb + 32 * 520);
            gcur[0] = __builtin_amdgcn_mfma_f32_16x16x32_bf16(ax[ks], b0, gcur[0], 0, 0, 0);
            gcur[1] = __builtin_amdgcn_mfma_f32_16x16x32_bf16(ax[ks], b1, gcur[1], 0, 0, 0);
            gcur[2] = __builtin_amdgcn_mfma_f32_16x16x32_bf16(ax[ks], b2, gcur[2], 0, 0, 0);
        }
        #pragma unroll
        for (int r = 0; r < 4; ++r) {
            int row = row0 + r;
            mcur[r] = smask[(((row >> 3) << 6) + 0) * 32 + (row & 7)];
        }
    }

    for (int t = 0; t < 64; ++t) {
        const _Float16* hsrc = (t & 1) ? hb : ha;
        _Float16*       hdst = (t & 1) ? ha : hb;

        half8 aA[16];
        {
            const unsigned long long* ap = (const unsigned long long*)
                (hsrc + (size_t)(rw0 + fr) * 512 + fq * 8);
            #pragma unroll
            for (int ks = 0; ks < 16; ++ks) {
                unsigned long long lo = __hip_atomic_load(ap + ks * 8,
                    __ATOMIC_RELAXED, __HIP_MEMORY_SCOPE_AGENT);
                unsigned long long hi = __hip_atomic_load(ap + ks * 8 + 1,
                    __ATOMIC_RELAXED, __HIP_MEMORY_SCOPE_AGENT);
                aA[ks] = h8_from(lo, hi);
            }
        }

        f32x4 acc[3] = {};
        #pragma unroll
        for (int ks = 0; ks < 16; ++ks) {
            const _Float16* bbase = &wh16[fr * 520 + ks * 32 + fq * 8];
            half8 b0 = *(const half8*)(bbase);
            half8 b1 = *(const half8*)(bbase + 16 * 520);
            half8 b2 = *(const half8*)(bbase + 32 * 520);
            acc[0] = __builtin_amdgcn_mfma_f32_16x16x32_f16(aA[ks], b0, acc[0], 0, 0, 0);
            acc[1] = __builtin_amdgcn_mfma_f32_16x16x32_f16(aA[ks], b1, acc[1], 0, 0, 0);
            acc[2] = __builtin_amdgcn_mfma_f32_16x16x32_f16(aA[ks], b2, acc[2], 0, 0, 0);
        }

        float hnv[4];
        #pragma unroll
        for (int r = 0; r < 4; ++r) {
            float rg = fsig(gcur[0][r] + bir + acc[0][r] + bhr);
            float zg = fsig(gcur[1][r] + biz + acc[1][r] + bhz);
            float ng = ftanh(gcur[2][r] + bin_ + rg * (acc[2][r] + bhn));
            float hn = (1.f - zg) * ng + zg * hp[r];
            hp[r] = hn;
            hnv[r] = hn;
            unsigned short hbits = __builtin_bit_cast(unsigned short, (_Float16)hn);
            __hip_atomic_store((unsigned short*)(hdst + (size_t)(row0 + r) * 512 + hcol),
                               hbits, __ATOMIC_RELAXED, __HIP_MEMORY_SCOPE_AGENT);
        }

        if (t != 63) {
            asm volatile("s_waitcnt vmcnt(0)" ::: "memory");
            __builtin_amdgcn_sched_barrier(0);
            if (lane == 0)
                __hip_atomic_store(flags + ((size_t)grp * 64 + t) * 64 + cu * 2 + wid, 1,
                                   __ATOMIC_RELAXED, __HIP_MEMORY_SCOPE_AGENT);
            #pragma unroll
            for (int r = 0; r < 4; ++r) {
                int row = row0 + r;
                int b_ = row >> 3, a_ = row & 7;
                hs_out[((size_t)((b_ << 6) + t) * 8 + a_) * 512 + hcol] =
                    mcur[r] ? 0.f : hnv[r];
            }
            f32x4 gnx[3] = {};
            {
                const short* xp = (const short*)xs +
                    ((size_t)(t + 1) * 256 + rw0 + fr) * 512 + fq * 8;
                short8 ax[16];
                #pragma unroll
                for (int ks = 0; ks < 16; ++ks) ax[ks] = *(const short8*)(xp + ks * 32);
                #pragma unroll
                for (int ks = 0; ks < 16; ++ks) {
                    const short* bb = &wi16[fr * 520 + ks * 32 + fq * 8];
                    short8 b0 = *(const short8*)(bb);
                    short8 b1 = *(const short8*)(bb + 16 * 520);
                    short8 b2 = *(const short8*)(bb + 32 * 520);
                    gnx[0] = __builtin_amdgcn_mfma_f32_16x16x32_bf16(ax[ks], b0, gnx[0], 0, 0, 0);
                    gnx[1] = __builtin_amdgcn_mfma_f32_16x16x32_bf16(ax[ks], b1, gnx[1], 0, 0, 0);
                    gnx[2] = __builtin_amdgcn_mfma_f32_16x16x32_bf16(ax[ks], b2, gnx[2], 0, 0, 0);
                }
            }
            int mnx[4];
            #pragma unroll
            for (int r = 0; r < 4; ++r) {
                int row = row0 + r;
                mnx[r] = smask[(((row >> 3) << 6) + (t + 1)) * 32 + (row & 7)];
            }
            const int* fp = flags + ((size_t)grp * 64 + t) * 64 + lane;
            long it = 0;
            for (;;) {
                int f = __hip_atomic_load(fp, __ATOMIC_RELAXED, __HIP_MEMORY_SCOPE_AGENT);
                if (__all(f != 0) || it > 100000000L) break;
                __builtin_amdgcn_s_sleep(1);
                ++it;
            }
            __builtin_amdgcn_sched_barrier(0);
            gcur[0] = gnx[0]; gcur[1] = gnx[1]; gcur[2] = gnx[2];
            mcur[0] = mnx[0]; mcur[1] = mnx[1]; mcur[2] = mnx[2]; mcur[3] = mnx[3];
        } else {
            #pragma unroll
            for (int r = 0; r < 4; ++r) {
                int row = row0 + r;
                int b_ = row >> 3, a_ = row & 7;
                hs_out[((size_t)((b_ << 6) + t) * 8 + a_) * 512 + hcol] =
                    mcur[r] ? 0.f : hnv[r];
            }
        }
    }
}

// ---------- launch ----------
extern "C" void kernel_launch(void* const* d_in, const int* in_sizes, int n_in,
                              void* d_out, int out_size, void* d_ws, size_t ws_size,
                              hipStream_t stream)
{
    const float* inputs = (const float*)d_in[0];
    const int*   obs    = (const int*)d_in[1];
    const int*   smask  = (const int*)d_in[2];
    const float* h0     = (const float*)d_in[3];
    const float* W1  = (const float*)d_in[4];  const float* b1  = (const float*)d_in[5];
    const float* Wq  = (const float*)d_in[6];  const float* bq  = (const float*)d_in[7];
    const float* Wk  = (const float*)d_in[8];  const float* bk  = (const float*)d_in[9];
    const float* Wv  = (const float*)d_in[10]; const float* bv  = (const float*)d_in[11];
    const float* Wih = (const float*)d_in[12]; const float* bih = (const float*)d_in[13];
    const float* Whh = (const float*)d_in[14]; const float* bhh = (const float*)d_in[15];
    const float* Wo  = (const float*)d_in[16]; const float* bo  = (const float*)d_in[17];

    char* ws = (char*)d_ws;
    bf16*  x    = (bf16*)(ws + 0);
    bf16*  xs   = (bf16*)(ws + 0);
    bf16*  qb   = (bf16*)(ws + 67108864ull);
    bf16*  kv   = (bf16*)(ws + 83886080ull);
    bf16*  W1t  = (bf16*)(ws + 218103808ull);
    bf16*  Wqt  = (bf16*)(ws + 218234880ull);
    bf16*  Wkvt = (bf16*)(ws + 218759168ull);
    _Float16* ha = (_Float16*)(ws + 219807744ull);
    _Float16* hb = (_Float16*)(ws + 220069888ull);
    int*   flags = (int*)(ws + 220332032ull);
    float* bkv  = (float*)(ws + 220463104ull);
    bf16*  Wot  = (bf16*)(ws + 220467200ull);

    float* out    = (float*)d_out;
    float* hs_out = out + 524288;

    hipMemsetAsync(flags, 0, 131072, stream);

    prep_all_k<<<dim3(1365), 256, 0, stream>>>(
        W1, Wq, Wk, Wv, Wo, h0, bk, bv, W1t, Wqt, Wkvt, Wot, ha, bkv);
    mfma_gemm_k<1, false, float, bf16><<<dim3(4, 512), 256, 0, stream>>>(
        inputs, W1t, b1, x, 65536, 512, 128);
    mfma_gemm_k<0, true, bf16, bf16><<<dim3(4, 128), 256, 0, stream>>>(
        x, Wqt, bq, qb, 16384, 512, 512);
    mfma_gemm_k<2, false, bf16, bf16><<<dim3(8, 512), 256, 0, stream>>>(
        x, Wkvt, bkv, kv, 65536, 1024, 512);
    attn_k<<<dim3(16384), 64, 0, stream>>>(qb, kv, kv + 512, obs, smask, xs, 1024);
    gru_xcd_k<<<dim3(256), 128, 0, stream>>>(
        xs, Wih, bih, Whh, bhh, h0, smask, hs_out, ha, hb, flags);
    qout_mfma_k<<<dim3(128), 256, 0, stream>>>(hs_out, Wot, bo, smask, out);
}